// Round 3
// baseline (122.882 us; speedup 1.0000x reference)
//
#include <hip/hip_runtime.h>
#include <hip/hip_bf16.h>

// ControlFieldModule (fp32 I/O), MFMA-bf16 GEMM version.
//   fiber = H @ Wf + bf                         [32768, 32]
//   h     = gelu([H|fiber] @ W1 + b1)           [32768, 64]
//   delta = clip(softplus(h @ w2 + b2), 0, 1)   [32768]
//   field = EMA(delta, 0.9) clip [0,10]; gate = sigmoid(-field)
// Fusion: one GEMM C[32768,96] = H @ [Wf | W1h + Wf@W1f] (bias folded),
// computed with v_mfma_f32_16x16x32_bf16.
// v4: occupancy doubled — 512 threads/block (8 waves), N-split between wave
// pairs (wave w: M-subtile w&3, N-half w>>2, 3 N-tiles each). 2 blocks/CU x
// 8 waves = 16 waves/CU = 4 waves/SIMD (was 2) to cover HBM latency.
// KC=256 (3 barriers), chunk-1 B pre-issued into regs (T14). A direct
// global->reg->frag. Delta reduce combines wave pairs via 512B LDS buffer.

#define NTOK  32768   // 8 * 4096
#define SEQ   4096
#define DM    512
#define NC    96      // 32 fiber + 64 control cols
#define TB    64      // tokens per block
#define KC    256     // K chunk
#define LROW  264     // padded LDS row stride in bf16 elems (528 B = 132 dw == 4 mod 32)

typedef short bf16x8 __attribute__((ext_vector_type(8)));
typedef float f32x4  __attribute__((ext_vector_type(4)));

__device__ __forceinline__ unsigned short f2bf(float f) {
    __hip_bfloat16 h = __float2bfloat16(f);
    return *reinterpret_cast<unsigned short*>(&h);
}

__device__ __forceinline__ bf16x8 cvt8(float4 u, float4 v) {
    bf16x8 r;
    r[0] = (short)f2bf(u.x); r[1] = (short)f2bf(u.y);
    r[2] = (short)f2bf(u.z); r[3] = (short)f2bf(u.w);
    r[4] = (short)f2bf(v.x); r[5] = (short)f2bf(v.y);
    r[6] = (short)f2bf(v.z); r[7] = (short)f2bf(v.w);
    return r;
}

// ---- kernel 1: build Wt = [Wf | W1h + Wf@W1f]^T as bf16 [96][512], bc fp32 [96]
__global__ __launch_bounds__(256)
void prep_kernel(const float* __restrict__ wf,   // [512,32]
                 const float* __restrict__ bfb,  // [32]
                 const float* __restrict__ w1,   // [544,64]
                 const float* __restrict__ b1,   // [64]
                 unsigned short* __restrict__ Wt, // [96,512] bf16
                 float* __restrict__ bc)          // [96]
{
    int idx = blockIdx.x * 256 + threadIdx.x;     // 0 .. 96*512-1
    if (idx < NC * DM) {
        int n = idx >> 9, k = idx & 511;
        float v;
        if (n < 32) {
            v = wf[k * 32 + n];
        } else {
            int c = n - 32;
            v = w1[k * 64 + c];
            const float4* wfr = (const float4*)(wf + k * 32);  // 128B contiguous per thread
#pragma unroll
            for (int f4 = 0; f4 < 8; ++f4) {
                float4 u = wfr[f4];
                v = fmaf(u.x, w1[(512 + f4 * 4 + 0) * 64 + c], v);
                v = fmaf(u.y, w1[(512 + f4 * 4 + 1) * 64 + c], v);
                v = fmaf(u.z, w1[(512 + f4 * 4 + 2) * 64 + c], v);
                v = fmaf(u.w, w1[(512 + f4 * 4 + 3) * 64 + c], v);
            }
        }
        Wt[idx] = f2bf(v);
    }
    if (idx < NC) {
        float v;
        if (idx < 32) {
            v = bfb[idx];
        } else {
            int c = idx - 32;
            v = b1[c];
            for (int f = 0; f < 32; ++f)
                v = fmaf(bfb[f], w1[(512 + f) * 64 + c], v);
        }
        bc[idx] = v;
    }
}

// ---- kernel 2: MFMA GEMM (M=64/block, N=96, K=512) + gelu/softplus epilogue
// 512 threads = 8 waves. Wave w: M-subtile rows [(w&3)*16, +16), N-half w>>2
// (3 of 6 N-tiles). A: direct global->reg->frag (lane l15 = row, quad*8 = k).
// B: 2 K-chunks staged in padded LDS; chunk-1 pre-issued into regs.
__global__ __launch_bounds__(512, 4)
void fused_gemm_kernel(const float* __restrict__ hidden,        // [NTOK,512]
                       const unsigned short* __restrict__ Wt,   // [96,512] bf16
                       const float* __restrict__ bc,            // [96]
                       const float* __restrict__ w2,            // [64]
                       const float* __restrict__ b2,            // [1]
                       float* __restrict__ out_delta,           // [NTOK]
                       float* __restrict__ out_fiber)           // [NTOK,32]
{
    __shared__ unsigned short b_lds[NC * LROW];   // 50688 B
    __shared__ float part[2][64];                 // delta partials per N-half

    const int tid   = threadIdx.x;
    const int wave  = tid >> 6;
    const int mwave = wave & 3;    // M-subtile
    const int nhalf = wave >> 2;   // N-half (tiles nhalf*3 .. nhalf*3+2)
    const int lane  = tid & 63;
    const int quad  = lane >> 4;
    const int l15   = lane & 15;
    const int tok0  = blockIdx.x * TB;

    // per-lane A base: row = tok0 + mwave*16 + l15, k base = quad*8
    const float* arow = hidden + (size_t)(tok0 + mwave * 16 + l15) * DM + quad * 8;

    f32x4 acc[3];
#pragma unroll
    for (int t = 0; t < 3; ++t) acc[t] = (f32x4){0.f, 0.f, 0.f, 0.f};

    // ---- stage B chunk 0 (kc=0): 96 rows x 256 k = 3072 x ushort8 / 512 thr ----
#pragma unroll
    for (int it = 0; it < 6; ++it) {
        int v   = it * 512 + tid;
        int row = v >> 5;             // 32 x ushort8 per row
        int c8  = v & 31;
        bf16x8 u = *(const bf16x8*)(Wt + row * DM + c8 * 8);
        *(bf16x8*)&b_lds[row * LROW + c8 * 8] = u;
    }
    __syncthreads();

    // ---- issue B chunk 1 (kc=256) loads now; they retire under compute-0 ----
    bf16x8 bstage[6];
#pragma unroll
    for (int it = 0; it < 6; ++it) {
        int v = it * 512 + tid;
        bstage[it] = *(const bf16x8*)(Wt + (v >> 5) * DM + KC + (v & 31) * 8);
    }

    // ---- compute chunk 0: ks = 0..7 over k in [0,256) ----
#pragma unroll
    for (int ks = 0; ks < 8; ++ks) {
        const float* ap = arow + ks * 32;
        float4 a0 = *(const float4*)ap;
        float4 a1 = *(const float4*)(ap + 4);
        bf16x8 af = cvt8(a0, a1);
#pragma unroll
        for (int ti = 0; ti < 3; ++ti) {
            int t = nhalf * 3 + ti;
            bf16x8 bfv = *(const bf16x8*)&b_lds[(t * 16 + l15) * LROW + ks * 32 + quad * 8];
            acc[ti] = __builtin_amdgcn_mfma_f32_16x16x32_bf16(af, bfv, acc[ti], 0, 0, 0);
        }
    }
    __syncthreads();

    // ---- write staged chunk 1 to LDS (loads already retired) ----
#pragma unroll
    for (int it = 0; it < 6; ++it) {
        int v = it * 512 + tid;
        *(bf16x8*)&b_lds[(v >> 5) * LROW + (v & 31) * 8] = bstage[it];
    }
    __syncthreads();

    // ---- compute chunk 1: k in [256,512) ----
#pragma unroll
    for (int ks = 0; ks < 8; ++ks) {
        const float* ap = arow + KC + ks * 32;
        float4 a0 = *(const float4*)ap;
        float4 a1 = *(const float4*)(ap + 4);
        bf16x8 af = cvt8(a0, a1);
#pragma unroll
        for (int ti = 0; ti < 3; ++ti) {
            int t = nhalf * 3 + ti;
            bf16x8 bfv = *(const bf16x8*)&b_lds[(t * 16 + l15) * LROW + ks * 32 + quad * 8];
            acc[ti] = __builtin_amdgcn_mfma_f32_16x16x32_bf16(af, bfv, acc[ti], 0, 0, 0);
        }
    }

    // ---- epilogue ----
    // C/D layout: col = lane&15 (within N-tile), row = quad*4 + reg.
    const int mbase = tok0 + mwave * 16 + quad * 4;

    float p0 = 0.f, p1 = 0.f, p2 = 0.f, p3 = 0.f;
    if (nhalf == 0) {
        // fiber tiles 0,1 -> out_fiber
#pragma unroll
        for (int ti = 0; ti < 2; ++ti) {
            int col = ti * 16 + l15;
            float bias = bc[col];
#pragma unroll
            for (int r = 0; r < 4; ++r)
                out_fiber[(size_t)(mbase + r) * 32 + col] = acc[ti][r] + bias;
        }
        // control tile 2: cols 0..15
        {
            int c = l15;
            float bias = bc[32 + c];
            float w2v  = w2[c];
            float x, g;
            x = acc[2][0] + bias; g = 0.5f * x * (1.f + erff(x * 0.70710678118f)); p0 = fmaf(g, w2v, p0);
            x = acc[2][1] + bias; g = 0.5f * x * (1.f + erff(x * 0.70710678118f)); p1 = fmaf(g, w2v, p1);
            x = acc[2][2] + bias; g = 0.5f * x * (1.f + erff(x * 0.70710678118f)); p2 = fmaf(g, w2v, p2);
            x = acc[2][3] + bias; g = 0.5f * x * (1.f + erff(x * 0.70710678118f)); p3 = fmaf(g, w2v, p3);
        }
    } else {
        // control tiles 3,4,5: cols 16..63
#pragma unroll
        for (int ti = 0; ti < 3; ++ti) {
            int c = 16 + ti * 16 + l15;
            float bias = bc[32 + c];
            float w2v  = w2[c];
            float x, g;
            x = acc[ti][0] + bias; g = 0.5f * x * (1.f + erff(x * 0.70710678118f)); p0 = fmaf(g, w2v, p0);
            x = acc[ti][1] + bias; g = 0.5f * x * (1.f + erff(x * 0.70710678118f)); p1 = fmaf(g, w2v, p1);
            x = acc[ti][2] + bias; g = 0.5f * x * (1.f + erff(x * 0.70710678118f)); p2 = fmaf(g, w2v, p2);
            x = acc[ti][3] + bias; g = 0.5f * x * (1.f + erff(x * 0.70710678118f)); p3 = fmaf(g, w2v, p3);
        }
    }
    // butterfly over the 16 lanes sharing this quad (masks 1,2,4,8 stay in-group)
#pragma unroll
    for (int m = 1; m <= 8; m <<= 1) {
        p0 += __shfl_xor(p0, m);
        p1 += __shfl_xor(p1, m);
        p2 += __shfl_xor(p2, m);
        p3 += __shfl_xor(p3, m);
    }
    if (l15 < 4) {
        float pv = (l15 == 0) ? p0 : (l15 == 1) ? p1 : (l15 == 2) ? p2 : p3;
        part[nhalf][mwave * 16 + quad * 4 + l15] = pv;
    }
    __syncthreads();
    if (tid < 64) {
        float s = part[0][tid] + part[1][tid] + b2[0];
        float d = (s > 0.f) ? s + log1pf(expf(-s)) : log1pf(expf(s));
        d = fminf(fmaxf(d, 0.f), 1.f);
        out_delta[tok0 + tid] = d;
    }
}

// ---- kernel 3: EMA as 128-tap causal FIR + gate ----
// tail truncation error = 0.9^128 ~ 1.4e-6 (vs 0.03 bf16 noise). 4 interleaved
// partial chains break the fmaf and weight-multiply dependency chains.
__global__ __launch_bounds__(256)
void scan_kernel(const float* __restrict__ delta,   // [8,4096]
                 const float* __restrict__ lam,     // scalar
                 float* __restrict__ out_gate,      // [NTOK]
                 float* __restrict__ out_field)     // [NTOK]
{
    __shared__ float lds_d[384];
    const int b     = blockIdx.x >> 4;   // batch row
    const int chunk = blockIdx.x & 15;   // 256-token chunk
    const int s0    = chunk * 256;
    const int tid   = threadIdx.x;

    for (int v = tid; v < 384; v += 256) {
        int s = s0 - 128 + v;
        lds_d[v] = (s >= 0) ? delta[b * SEQ + s] : 0.f;
    }
    __syncthreads();

    const int base = 128 + tid;
    const float r4 = 0.6561f;            // 0.9^4
    float w0 = 0.1f, w1v = 0.09f, w2v = 0.081f, w3v = 0.0729f;
    float p0 = 0.f, p1 = 0.f, p2 = 0.f, p3 = 0.f;
#pragma unroll
    for (int j = 0; j < 128; j += 4) {
        p0 = fmaf(w0,  lds_d[base - j],     p0); w0  *= r4;
        p1 = fmaf(w1v, lds_d[base - j - 1], p1); w1v *= r4;
        p2 = fmaf(w2v, lds_d[base - j - 2], p2); w2v *= r4;
        p3 = fmaf(w3v, lds_d[base - j - 3], p3); w3v *= r4;
    }
    float field = fminf(fmaxf((p0 + p1) + (p2 + p3), 0.f), 10.f);

    float gate = 1.f / (1.f + expf(lam[0] * field));
    int t = b * SEQ + s0 + tid;
    out_field[t] = field;
    out_gate[t]  = gate;
}

// ---- launcher ----
extern "C" void kernel_launch(void* const* d_in, const int* in_sizes, int n_in,
                              void* d_out, int out_size, void* d_ws, size_t ws_size,
                              hipStream_t stream)
{
    const float* hidden = (const float*)d_in[0];
    const float* wf     = (const float*)d_in[1];
    const float* bfb    = (const float*)d_in[2];
    const float* w1     = (const float*)d_in[3];
    const float* b1     = (const float*)d_in[4];
    const float* w2     = (const float*)d_in[5];
    const float* b2     = (const float*)d_in[6];
    const float* lam    = (const float*)d_in[7];
    float* out = (float*)d_out;
    // out layout: gate[32768] | field[32768] | delta[32768] | fiber[32768*32]
    float* out_gate  = out;
    float* out_field = out + NTOK;
    float* out_delta = out + 2 * NTOK;
    float* out_fiber = out + 3 * NTOK;

    unsigned short* Wt = (unsigned short*)d_ws;                 // 96*512*2 = 98304 B
    float* bc          = (float*)((char*)d_ws + NC * DM * 2);   // 384 B

    hipLaunchKernelGGL(prep_kernel, dim3((NC * DM + 255) / 256), dim3(256), 0, stream,
                       wf, bfb, w1, b1, Wt, bc);
    hipLaunchKernelGGL(fused_gemm_kernel, dim3(NTOK / TB), dim3(512), 0, stream,
                       hidden, Wt, bc, w2, b2, out_delta, out_fiber);
    hipLaunchKernelGGL(scan_kernel, dim3(128), dim3(256), 0, stream,
                       out_delta, lam, out_gate, out_field);
}

// Round 4
// 117.632 us; speedup vs baseline: 1.0446x; 1.0446x over previous
//
#include <hip/hip_runtime.h>
#include <hip/hip_bf16.h>

// ControlFieldModule (fp32 I/O), MFMA-bf16 GEMM version.
//   fiber = H @ Wf + bf                         [32768, 32]
//   h     = gelu([H|fiber] @ W1 + b1)           [32768, 64]
//   delta = clip(softplus(h @ w2 + b2), 0, 1)   [32768]
//   field = EMA(delta, 0.9) clip [0,10]; gate = sigmoid(-field)
// Fusion: one GEMM C[32768,96] = H @ [Wf | W1h + Wf@W1f] (bias folded),
// computed with v_mfma_f32_16x16x32_bf16 (inputs rounded to bf16; threshold
// 0.11 >> expected ~3e-2 error). EMA == 256-tap causal FIR (0.9^256 ~ 2e-12).
// v5: REVERT to best-measured configuration (116.1/117.7 us). Rounds 1-3
// tested A-direct staging, KC=256 async-B, and 2x occupancy: all null
// (117.7/120.2/119.2/122.9 us, within noise) -> timed region is dominated
// by harness poison fills (41 us each @ 82% HBM peak) + the GEMM's
// mandatory 64 MiB hidden read at the HBM floor. Keeping the variant with
// the best measurements.

#define NTOK  32768   // 8 * 4096
#define SEQ   4096
#define DM    512
#define NC    96      // 32 fiber + 64 control cols
#define TB    64      // tokens per block
#define KC    128     // K chunk
#define LROW  136     // padded LDS row stride in bf16 elems (272 B = 68 dw ≡ 4 mod 32 -> 2-way free)

typedef short bf16x8 __attribute__((ext_vector_type(8)));
typedef float f32x4  __attribute__((ext_vector_type(4)));

__device__ __forceinline__ unsigned short f2bf(float f) {
    __hip_bfloat16 h = __float2bfloat16(f);
    return *reinterpret_cast<unsigned short*>(&h);
}

// ---- kernel 1: build Wt = [Wf | W1h + Wf@W1f]^T as bf16 [96][512], bc fp32 [96]
__global__ __launch_bounds__(256)
void prep_kernel(const float* __restrict__ wf,   // [512,32]
                 const float* __restrict__ bfb,  // [32]
                 const float* __restrict__ w1,   // [544,64]
                 const float* __restrict__ b1,   // [64]
                 unsigned short* __restrict__ Wt, // [96,512] bf16
                 float* __restrict__ bc)          // [96]
{
    int idx = blockIdx.x * 256 + threadIdx.x;     // 0 .. 96*512-1
    if (idx < NC * DM) {
        int n = idx >> 9, k = idx & 511;
        float v;
        if (n < 32) {
            v = wf[k * 32 + n];
        } else {
            int c = n - 32;
            v = w1[k * 64 + c];
            for (int f = 0; f < 32; ++f)
                v = fmaf(wf[k * 32 + f], w1[(512 + f) * 64 + c], v);
        }
        Wt[idx] = f2bf(v);
    }
    if (idx < NC) {
        float v;
        if (idx < 32) {
            v = bfb[idx];
        } else {
            int c = idx - 32;
            v = b1[c];
            for (int f = 0; f < 32; ++f)
                v = fmaf(bfb[f], w1[(512 + f) * 64 + c], v);
        }
        bc[idx] = v;
    }
}

// ---- kernel 2: MFMA GEMM (M=64/block, N=96, K=512) + gelu/softplus epilogue
// 256 threads = 4 waves; wave w owns M-tile rows [w*16, w*16+16), all 6 N-tiles.
__global__ __launch_bounds__(256, 2)
void fused_gemm_kernel(const float* __restrict__ hidden,        // [NTOK,512]
                       const unsigned short* __restrict__ Wt,   // [96,512] bf16
                       const float* __restrict__ bc,            // [96]
                       const float* __restrict__ w2,            // [64]
                       const float* __restrict__ b2,            // [1]
                       float* __restrict__ out_delta,           // [NTOK]
                       float* __restrict__ out_fiber)           // [NTOK,32]
{
    __shared__ unsigned short a_lds[TB * LROW];   // 17408 B
    __shared__ unsigned short b_lds[NC * LROW];   // 26112 B

    const int tid  = threadIdx.x;
    const int wave = tid >> 6;
    const int lane = tid & 63;
    const int quad = lane >> 4;
    const int l15  = lane & 15;
    const int tok0 = blockIdx.x * TB;

    f32x4 acc[6];
#pragma unroll
    for (int t = 0; t < 6; ++t) acc[t] = (f32x4){0.f, 0.f, 0.f, 0.f};

    for (int kc = 0; kc < DM; kc += KC) {
        // stage A: 64 tokens x 128 k, fp32 -> bf16 (2048 float4 / 256 thr)
#pragma unroll
        for (int it = 0; it < 8; ++it) {
            int v   = it * 256 + tid;
            int row = v >> 5;             // 32 float4 per row
            int c4  = v & 31;
            float4 u = *(const float4*)(hidden + (size_t)(tok0 + row) * DM + kc + c4 * 4);
            ushort4 o;
            o.x = f2bf(u.x); o.y = f2bf(u.y); o.z = f2bf(u.z); o.w = f2bf(u.w);
            *(ushort4*)&a_lds[row * LROW + c4 * 4] = o;
        }
        // stage B: 96 rows x 128 k bf16 (1536 x 16B / 256 thr)
#pragma unroll
        for (int it = 0; it < 6; ++it) {
            int v   = it * 256 + tid;
            int row = v >> 4;             // 16 x ushort8 per row
            int c8  = v & 15;
            bf16x8 u = *(const bf16x8*)(Wt + row * DM + kc + c8 * 8);
            *(bf16x8*)&b_lds[row * LROW + c8 * 8] = u;
        }
        __syncthreads();

#pragma unroll
        for (int ks = 0; ks < 4; ++ks) {
            bf16x8 af = *(const bf16x8*)&a_lds[(wave * 16 + l15) * LROW + ks * 32 + quad * 8];
#pragma unroll
            for (int t = 0; t < 6; ++t) {
                bf16x8 bfv = *(const bf16x8*)&b_lds[(t * 16 + l15) * LROW + ks * 32 + quad * 8];
                acc[t] = __builtin_amdgcn_mfma_f32_16x16x32_bf16(af, bfv, acc[t], 0, 0, 0);
            }
        }
        __syncthreads();
    }

    // ---- epilogue ----
    // C/D layout: col = lane&15 (within N-tile), row = quad*4 + reg.
    const int mbase = tok0 + wave * 16 + quad * 4;

    // fiber tiles 0,1 -> out_fiber
#pragma unroll
    for (int t = 0; t < 2; ++t) {
        int col = t * 16 + l15;
        float bias = bc[col];
#pragma unroll
        for (int r = 0; r < 4; ++r)
            out_fiber[(size_t)(mbase + r) * 32 + col] = acc[t][r] + bias;
    }

    // control tiles 2..5: gelu(x)*w2, reduce 64 cols -> delta
    float p0 = 0.f, p1 = 0.f, p2 = 0.f, p3 = 0.f;
#pragma unroll
    for (int t = 2; t < 6; ++t) {
        int c = (t - 2) * 16 + l15;
        float bias = bc[32 + c];
        float w2v  = w2[c];
        float x, g;
        x = acc[t][0] + bias; g = 0.5f * x * (1.f + erff(x * 0.70710678118f)); p0 = fmaf(g, w2v, p0);
        x = acc[t][1] + bias; g = 0.5f * x * (1.f + erff(x * 0.70710678118f)); p1 = fmaf(g, w2v, p1);
        x = acc[t][2] + bias; g = 0.5f * x * (1.f + erff(x * 0.70710678118f)); p2 = fmaf(g, w2v, p2);
        x = acc[t][3] + bias; g = 0.5f * x * (1.f + erff(x * 0.70710678118f)); p3 = fmaf(g, w2v, p3);
    }
    // butterfly over the 16 lanes sharing this quad (masks 1,2,4,8 stay in-group)
#pragma unroll
    for (int m = 1; m <= 8; m <<= 1) {
        p0 += __shfl_xor(p0, m);
        p1 += __shfl_xor(p1, m);
        p2 += __shfl_xor(p2, m);
        p3 += __shfl_xor(p3, m);
    }
    if (l15 < 4) {
        float pv = (l15 == 0) ? p0 : (l15 == 1) ? p1 : (l15 == 2) ? p2 : p3;
        float s = pv + b2[0];
        float d = (s > 0.f) ? s + log1pf(expf(-s)) : log1pf(expf(s));
        d = fminf(fmaxf(d, 0.f), 1.f);
        out_delta[mbase + l15] = d;
    }
}

// ---- kernel 3: EMA as 256-tap causal FIR + gate ----
__global__ __launch_bounds__(256)
void scan_kernel(const float* __restrict__ delta,   // [8,4096]
                 const float* __restrict__ lam,     // scalar
                 float* __restrict__ out_gate,      // [NTOK]
                 float* __restrict__ out_field)     // [NTOK]
{
    __shared__ float lds_d[512];
    const int b     = blockIdx.x >> 4;   // batch row
    const int chunk = blockIdx.x & 15;   // 256-token chunk
    const int s0    = chunk * 256;
    const int tid   = threadIdx.x;

    for (int v = tid; v < 512; v += 256) {
        int s = s0 - 256 + v;
        lds_d[v] = (s >= 0) ? delta[b * SEQ + s] : 0.f;
    }
    __syncthreads();

    float w = 0.1f, acc = 0.f;
    const int base = 256 + tid;
    for (int j = 0; j < 256; ++j) {
        acc = fmaf(w, lds_d[base - j], acc);
        w *= 0.9f;
    }
    float field = fminf(fmaxf(acc, 0.f), 10.f);

    float gate = 1.f / (1.f + expf(lam[0] * field));
    int t = b * SEQ + s0 + tid;
    out_field[t] = field;
    out_gate[t]  = gate;
}

// ---- launcher ----
extern "C" void kernel_launch(void* const* d_in, const int* in_sizes, int n_in,
                              void* d_out, int out_size, void* d_ws, size_t ws_size,
                              hipStream_t stream)
{
    const float* hidden = (const float*)d_in[0];
    const float* wf     = (const float*)d_in[1];
    const float* bfb    = (const float*)d_in[2];
    const float* w1     = (const float*)d_in[3];
    const float* b1     = (const float*)d_in[4];
    const float* w2     = (const float*)d_in[5];
    const float* b2     = (const float*)d_in[6];
    const float* lam    = (const float*)d_in[7];
    float* out = (float*)d_out;
    // out layout: gate[32768] | field[32768] | delta[32768] | fiber[32768*32]
    float* out_gate  = out;
    float* out_field = out + NTOK;
    float* out_delta = out + 2 * NTOK;
    float* out_fiber = out + 3 * NTOK;

    unsigned short* Wt = (unsigned short*)d_ws;                 // 96*512*2 = 98304 B
    float* bc          = (float*)((char*)d_ws + NC * DM * 2);   // 384 B

    hipLaunchKernelGGL(prep_kernel, dim3((NC * DM + 255) / 256), dim3(256), 0, stream,
                       wf, bfb, w1, b1, Wt, bc);
    hipLaunchKernelGGL(fused_gemm_kernel, dim3(NTOK / TB), dim3(256), 0, stream,
                       hidden, Wt, bc, w2, b2, out_delta, out_fiber);
    hipLaunchKernelGGL(scan_kernel, dim3(128), dim3(256), 0, stream,
                       out_delta, lam, out_gate, out_field);
}